// Round 1
// baseline (509.904 us; speedup 1.0000x reference)
//
#include <hip/hip_runtime.h>

#define NN   131072
#define LVLS 8
#define NPL  16384
#define DEG  16
#define DIM  128
#define HID  64

__device__ __forceinline__ float lrelu(float x) { return x >= 0.f ? x : 0.01f * x; }

// Per-wave: push 4 nodes through MLP(DIM->HID->HID->DIM) with LeakyReLU(0.01)
// after layers 1 and 2. xs: this wave's [4][DIM] inputs in LDS. y1s/y2s: [4][HID]
// LDS scratch. Outputs: lo[t] = out[lane], hi[t] = out[lane+64] for node t.
// Weight loads are lane-coalesced 256B vector loads, L1/L2-hit (weights ~80KB,
// shared by every wave on the chip), amortized over 4 nodes per load.
__device__ __forceinline__ void mlp_wave4(
    const float* __restrict__ w1, const float* __restrict__ b1,
    const float* __restrict__ w2, const float* __restrict__ b2,
    const float* __restrict__ w3, const float* __restrict__ b3,
    float (*__restrict__ xs)[DIM],
    float (*__restrict__ y1s)[HID],
    float (*__restrict__ y2s)[HID],
    int lane, float lo[4], float hi[4])
{
    // ---- layer 1: [4][128] @ [128][64], lane computes output column `lane`
    float a0 = b1[lane], a1 = a0, a2 = a0, a3 = a0;
#pragma unroll 16
    for (int i = 0; i < DIM; ++i) {
        float wv = w1[i * HID + lane];
        a0 = fmaf(xs[0][i], wv, a0);
        a1 = fmaf(xs[1][i], wv, a1);
        a2 = fmaf(xs[2][i], wv, a2);
        a3 = fmaf(xs[3][i], wv, a3);
    }
    y1s[0][lane] = lrelu(a0);
    y1s[1][lane] = lrelu(a1);
    y1s[2][lane] = lrelu(a2);
    y1s[3][lane] = lrelu(a3);
    __syncthreads();

    // ---- layer 2: [4][64] @ [64][64]
    float c0 = b2[lane], c1 = c0, c2 = c0, c3 = c0;
#pragma unroll 16
    for (int i = 0; i < HID; ++i) {
        float wv = w2[i * HID + lane];
        c0 = fmaf(y1s[0][i], wv, c0);
        c1 = fmaf(y1s[1][i], wv, c1);
        c2 = fmaf(y1s[2][i], wv, c2);
        c3 = fmaf(y1s[3][i], wv, c3);
    }
    y2s[0][lane] = lrelu(c0);
    y2s[1][lane] = lrelu(c1);
    y2s[2][lane] = lrelu(c2);
    y2s[3][lane] = lrelu(c3);
    __syncthreads();

    // ---- layer 3: [4][64] @ [64][128], lane computes columns lane and lane+64
    float t0 = b3[lane], t1 = b3[64 + lane];
    lo[0] = t0; lo[1] = t0; lo[2] = t0; lo[3] = t0;
    hi[0] = t1; hi[1] = t1; hi[2] = t1; hi[3] = t1;
#pragma unroll 8
    for (int i = 0; i < HID; ++i) {
        float wl = w3[i * DIM + lane];
        float wh = w3[i * DIM + 64 + lane];
        float s0 = y2s[0][i], s1 = y2s[1][i], s2 = y2s[2][i], s3 = y2s[3][i];
        lo[0] = fmaf(s0, wl, lo[0]); hi[0] = fmaf(s0, wh, hi[0]);
        lo[1] = fmaf(s1, wl, lo[1]); hi[1] = fmaf(s1, wh, hi[1]);
        lo[2] = fmaf(s2, wl, lo[2]); hi[2] = fmaf(s2, wh, hi[2]);
        lo[3] = fmaf(s3, wl, lo[3]); hi[3] = fmaf(s3, wh, hi[3]);
    }
}

// inv_h[row] = inv_mlp(h[row]) for rows [rowBase, rowBase + NPL).
// block = 256 (4 waves), 4 nodes per wave -> 16 nodes/block, grid = NPL/16.
__global__ __launch_bounds__(256) void inv_kernel(
    const float* __restrict__ hbuf, float* __restrict__ invbuf,
    const float* __restrict__ w1, const float* __restrict__ b1,
    const float* __restrict__ w2, const float* __restrict__ b2,
    const float* __restrict__ w3, const float* __restrict__ b3,
    int rowBase)
{
    __shared__ float xs[16][DIM];
    __shared__ float y1s[16][HID];
    __shared__ float y2s[16][HID];

    int lane = threadIdx.x & 63;
    int w    = threadIdx.x >> 6;
    int nb   = blockIdx.x * 16 + w * 4;   // first of this wave's 4 local nodes

#pragma unroll
    for (int t = 0; t < 4; ++t) {
        size_t row = (size_t)(rowBase + nb + t) * DIM;
        float2 v = *(const float2*)&hbuf[row + lane * 2];
        xs[w * 4 + t][lane * 2]     = v.x;
        xs[w * 4 + t][lane * 2 + 1] = v.y;
    }
    __syncthreads();

    float lo[4], hi[4];
    mlp_wave4(w1, b1, w2, b2, w3, b3,
              &xs[w * 4], &y1s[w * 4], &y2s[w * 4], lane, lo, hi);

#pragma unroll
    for (int t = 0; t < 4; ++t) {
        size_t row = (size_t)(rowBase + nb + t) * DIM;
        invbuf[row + lane]      = lo[t];
        invbuf[row + 64 + lane] = hi[t];
    }
}

// For dst rows [dstBase, dstBase + NPL): gather DEG=16 source rows
// (mask ? inv_h : h), mean, and-MLP, write h[dst].
// esrc/emask already offset to this level's [NPL][DEG] slab.
__global__ __launch_bounds__(256) void agg_kernel(
    float* __restrict__ hbuf, const float* __restrict__ invbuf,
    const int* __restrict__ esrc, const int* __restrict__ emask,
    const float* __restrict__ w1, const float* __restrict__ b1,
    const float* __restrict__ w2, const float* __restrict__ b2,
    const float* __restrict__ w3, const float* __restrict__ b3,
    int dstBase)
{
    __shared__ float xs[16][DIM];
    __shared__ float y1s[16][HID];
    __shared__ float y2s[16][HID];

    int lane   = threadIdx.x & 63;
    int w      = threadIdx.x >> 6;
    int e_lane = lane & 15;
    int t_lane = lane >> 4;
    int nb     = blockIdx.x * 16 + w * 4;

    // lanes 0-15 hold node t=0's 16 edges, lanes 16-31 node t=1, etc.
    int myIdx = esrc[(nb + t_lane) * DEG + e_lane];
    int myMsk = emask[(nb + t_lane) * DEG + e_lane];

    float ax0 = 0.f, ay0 = 0.f, ax1 = 0.f, ay1 = 0.f;
    float ax2 = 0.f, ay2 = 0.f, ax3 = 0.f, ay3 = 0.f;

#pragma unroll
    for (int e = 0; e < DEG; ++e) {
        {
            int s = __shfl(myIdx, 0 * 16 + e, 64);
            int m = __shfl(myMsk, 0 * 16 + e, 64);
            const float* p = m ? invbuf : hbuf;
            float2 v = *(const float2*)&p[(size_t)s * DIM + lane * 2];
            ax0 += v.x; ay0 += v.y;
        }
        {
            int s = __shfl(myIdx, 1 * 16 + e, 64);
            int m = __shfl(myMsk, 1 * 16 + e, 64);
            const float* p = m ? invbuf : hbuf;
            float2 v = *(const float2*)&p[(size_t)s * DIM + lane * 2];
            ax1 += v.x; ay1 += v.y;
        }
        {
            int s = __shfl(myIdx, 2 * 16 + e, 64);
            int m = __shfl(myMsk, 2 * 16 + e, 64);
            const float* p = m ? invbuf : hbuf;
            float2 v = *(const float2*)&p[(size_t)s * DIM + lane * 2];
            ax2 += v.x; ay2 += v.y;
        }
        {
            int s = __shfl(myIdx, 3 * 16 + e, 64);
            int m = __shfl(myMsk, 3 * 16 + e, 64);
            const float* p = m ? invbuf : hbuf;
            float2 v = *(const float2*)&p[(size_t)s * DIM + lane * 2];
            ax3 += v.x; ay3 += v.y;
        }
    }

    const float inv16 = 0.0625f;  // mean over DEG=16, exact
    xs[w * 4 + 0][lane * 2] = ax0 * inv16; xs[w * 4 + 0][lane * 2 + 1] = ay0 * inv16;
    xs[w * 4 + 1][lane * 2] = ax1 * inv16; xs[w * 4 + 1][lane * 2 + 1] = ay1 * inv16;
    xs[w * 4 + 2][lane * 2] = ax2 * inv16; xs[w * 4 + 2][lane * 2 + 1] = ay2 * inv16;
    xs[w * 4 + 3][lane * 2] = ax3 * inv16; xs[w * 4 + 3][lane * 2 + 1] = ay3 * inv16;
    __syncthreads();

    float lo[4], hi[4];
    mlp_wave4(w1, b1, w2, b2, w3, b3,
              &xs[w * 4], &y1s[w * 4], &y2s[w * 4], lane, lo, hi);

#pragma unroll
    for (int t = 0; t < 4; ++t) {
        size_t row = (size_t)(dstBase + nb + t) * DIM;
        hbuf[row + lane]      = lo[t];
        hbuf[row + 64 + lane] = hi[t];
    }
}

extern "C" void kernel_launch(void* const* d_in, const int* in_sizes, int n_in,
                              void* d_out, int out_size, void* d_ws, size_t ws_size,
                              hipStream_t stream)
{
    const float* h     = (const float*)d_in[0];
    const int*   esrc  = (const int*)d_in[1];   // [L-1][NPL][DEG]
    const int*   emask = (const int*)d_in[2];   // [L-1][NPL][DEG]
    const float* iw1 = (const float*)d_in[3];
    const float* ib1 = (const float*)d_in[4];
    const float* iw2 = (const float*)d_in[5];
    const float* ib2 = (const float*)d_in[6];
    const float* iw3 = (const float*)d_in[7];
    const float* ib3 = (const float*)d_in[8];
    const float* aw1 = (const float*)d_in[9];
    const float* ab1 = (const float*)d_in[10];
    const float* aw2 = (const float*)d_in[11];
    const float* ab2 = (const float*)d_in[12];
    const float* aw3 = (const float*)d_in[13];
    const float* ab3 = (const float*)d_in[14];

    float* out = (float*)d_out;          // h, updated level by level
    float* inv = (float*)d_ws;           // inv_h rows for levels 0..6 (~59 MB)

    // level 0 rows pass through unchanged; later levels overwritten in place
    hipMemcpyAsync(out, h, (size_t)NN * DIM * sizeof(float),
                   hipMemcpyDeviceToDevice, stream);

    const int grid = NPL / 16;  // 1024 blocks, 16 nodes/block

    // inv_h for level 0
    inv_kernel<<<grid, 256, 0, stream>>>(out, inv, iw1, ib1, iw2, ib2, iw3, ib3, 0);

    for (int lvl = 1; lvl < LVLS; ++lvl) {
        agg_kernel<<<grid, 256, 0, stream>>>(
            out, inv,
            esrc  + (size_t)(lvl - 1) * NPL * DEG,
            emask + (size_t)(lvl - 1) * NPL * DEG,
            aw1, ab1, aw2, ab2, aw3, ab3,
            lvl * NPL);
        if (lvl < LVLS - 1) {
            inv_kernel<<<grid, 256, 0, stream>>>(
                out, inv, iw1, ib1, iw2, ib2, iw3, ib3, lvl * NPL);
        }
    }
}